// Round 1
// baseline (1005.411 us; speedup 1.0000x reference)
//
#include <hip/hip_runtime.h>

#define N_NODES 100000
#define N_EDGES 1600000
#define HID 128
#define N_PRED 8

// ---------------- degree histogram ----------------
__global__ void deg_kernel(const int* __restrict__ src, const int* __restrict__ dst,
                           unsigned* __restrict__ degOut, unsigned* __restrict__ degIn) {
    int e = blockIdx.x * blockDim.x + threadIdx.x;
    if (e < N_EDGES) {
        atomicAdd(&degOut[src[e]], 1u);
        atomicAdd(&degIn[dst[e]], 1u);
    }
}

// ---------------- prefix scan (3 kernels) ----------------
__global__ void scan1_kernel(const unsigned* __restrict__ degIn,
                             unsigned* __restrict__ rowEnd,
                             unsigned* __restrict__ blockSums) {
    __shared__ unsigned tmp[256];
    int t = threadIdx.x;
    int i = blockIdx.x * 256 + t;
    unsigned v = (i < N_NODES) ? degIn[i] : 0u;
    tmp[t] = v;
    __syncthreads();
    for (int off = 1; off < 256; off <<= 1) {
        unsigned a = (t >= off) ? tmp[t - off] : 0u;
        __syncthreads();
        tmp[t] += a;
        __syncthreads();
    }
    if (i < N_NODES) rowEnd[i] = tmp[t];       // inclusive, chunk-local
    if (t == 255) blockSums[blockIdx.x] = tmp[255];
}

__global__ void scan2_kernel(unsigned* blockSums, int n) {
    __shared__ unsigned tmp[512];
    int t = threadIdx.x;
    unsigned v = (t < n) ? blockSums[t] : 0u;
    tmp[t] = v;
    __syncthreads();
    for (int off = 1; off < 512; off <<= 1) {
        unsigned a = (t >= off) ? tmp[t - off] : 0u;
        __syncthreads();
        tmp[t] += a;
        __syncthreads();
    }
    if (t < n) blockSums[t] = tmp[t];          // inclusive scan of block sums
}

__global__ void scan3_kernel(unsigned* __restrict__ rowEnd, unsigned* __restrict__ counters,
                             const unsigned* __restrict__ blockSums,
                             const unsigned* __restrict__ degIn,
                             const unsigned* __restrict__ degOut,
                             float* __restrict__ normIn, float* __restrict__ normOut) {
    int i = blockIdx.x * 256 + threadIdx.x;
    if (i >= N_NODES) return;
    unsigned add = blockIdx.x ? blockSums[blockIdx.x - 1] : 0u;
    unsigned re = rowEnd[i] + add;
    rowEnd[i] = re;                 // global inclusive prefix (row end)
    counters[i] = re - degIn[i];    // row start (exclusive prefix)
    unsigned di = degIn[i], dox = degOut[i];
    normIn[i]  = di  ? rsqrtf((float)di)  : 0.0f;
    normOut[i] = dox ? rsqrtf((float)dox) : 0.0f;
}

// ---------------- CSR edge placement (by dst) ----------------
__global__ void place_kernel(const int* __restrict__ src, const int* __restrict__ dst,
                             unsigned* __restrict__ counters, int* __restrict__ csrSrc) {
    int e = blockIdx.x * blockDim.x + threadIdx.x;
    if (e < N_EDGES) {
        unsigned p = atomicAdd(&counters[dst[e]], 1u);
        csrSrc[p] = src[e];
    }
}

// ---------------- gather-form SpMM: out[d] = sum_{e: dst=d} h[src_e] * normOut[src_e] ----------------
__global__ void gather_spmm(const float* __restrict__ h, const float* __restrict__ normOut,
                            const int* __restrict__ csrSrc, const unsigned* __restrict__ rowEnd,
                            float* __restrict__ out) {
    int gid = blockIdx.x * blockDim.x + threadIdx.x;
    int row = gid >> 5;          // 32 lanes per row, 4 floats per lane
    int lane = gid & 31;
    if (row >= N_NODES) return;
    unsigned start = row ? rowEnd[row - 1] : 0u;
    unsigned end = rowEnd[row];
    float ax = 0.f, ay = 0.f, az = 0.f, aw = 0.f;
    const float4* h4 = (const float4*)h;
    for (unsigned k = start; k < end; ++k) {
        int s = csrSrc[k];
        float no = normOut[s];
        float4 v = h4[(size_t)s * 32 + lane];
        ax = fmaf(v.x, no, ax);
        ay = fmaf(v.y, no, ay);
        az = fmaf(v.z, no, az);
        aw = fmaf(v.w, no, aw);
    }
    float4 o; o.x = ax; o.y = ay; o.z = az; o.w = aw;
    ((float4*)out)[(size_t)row * 32 + lane] = o;
}

// ---------------- in-place GEMM + norm_in + bias + relu ----------------
// M[row,:] <- relu(normIn[row] * (M[row,:] @ W) + b)
__launch_bounds__(256, 2)
__global__ void gemm_relu_inplace(float* __restrict__ M, const float* __restrict__ W,
                                  const float* __restrict__ b, const float* __restrict__ normIn,
                                  int rowsPerBlock) {
    __shared__ float Wl[128 * 128];   // 64 KB
    __shared__ float Ml[32 * 128];    // 16 KB
    int tid = threadIdx.x;
    for (int i = tid * 4; i < 128 * 128; i += 256 * 4)
        *(float4*)&Wl[i] = *(const float4*)&W[i];
    int cg = tid & 31;   // column group: cols cg*4 .. cg*4+3
    int rg = tid >> 5;   // row group:    rows rg*4 .. rg*4+3 within tile
    float4 bb = ((const float4*)b)[cg];
    __syncthreads();

    int rowStart = blockIdx.x * rowsPerBlock;
    int rowStop = min(rowStart + rowsPerBlock, N_NODES);
    for (int r0 = rowStart; r0 < rowStop; r0 += 32) {
        int nr = min(32, rowStop - r0);
        __syncthreads();   // all readers of Ml from prev tile done
        for (int i = tid; i < nr * 32; i += 256)
            ((float4*)Ml)[i] = ((const float4*)M)[(size_t)r0 * 32 + i];
        __syncthreads();

        float4 a0 = {0,0,0,0}, a1 = {0,0,0,0}, a2 = {0,0,0,0}, a3 = {0,0,0,0};
        const float* m0p = &Ml[(rg * 4 + 0) * 128];
        const float* m1p = &Ml[(rg * 4 + 1) * 128];
        const float* m2p = &Ml[(rg * 4 + 2) * 128];
        const float* m3p = &Ml[(rg * 4 + 3) * 128];
        for (int k = 0; k < 128; k += 4) {
            float4 mv0 = *(const float4*)&m0p[k];
            float4 mv1 = *(const float4*)&m1p[k];
            float4 mv2 = *(const float4*)&m2p[k];
            float4 mv3 = *(const float4*)&m3p[k];
#pragma unroll
            for (int kk = 0; kk < 4; ++kk) {
                float4 w4 = *(const float4*)&Wl[(k + kk) * 128 + cg * 4];
                float f0 = ((const float*)&mv0)[kk];
                float f1 = ((const float*)&mv1)[kk];
                float f2 = ((const float*)&mv2)[kk];
                float f3 = ((const float*)&mv3)[kk];
                a0.x = fmaf(w4.x, f0, a0.x); a0.y = fmaf(w4.y, f0, a0.y);
                a0.z = fmaf(w4.z, f0, a0.z); a0.w = fmaf(w4.w, f0, a0.w);
                a1.x = fmaf(w4.x, f1, a1.x); a1.y = fmaf(w4.y, f1, a1.y);
                a1.z = fmaf(w4.z, f1, a1.z); a1.w = fmaf(w4.w, f1, a1.w);
                a2.x = fmaf(w4.x, f2, a2.x); a2.y = fmaf(w4.y, f2, a2.y);
                a2.z = fmaf(w4.z, f2, a2.z); a2.w = fmaf(w4.w, f2, a2.w);
                a3.x = fmaf(w4.x, f3, a3.x); a3.y = fmaf(w4.y, f3, a3.y);
                a3.z = fmaf(w4.z, f3, a3.z); a3.w = fmaf(w4.w, f3, a3.w);
            }
        }

        int baseRow = r0 + rg * 4;
#pragma unroll
        for (int rr = 0; rr < 4; ++rr) {
            int row = baseRow + rr;
            if (row < rowStop) {
                float ni = normIn[row];
                float4 av = (rr == 0) ? a0 : (rr == 1) ? a1 : (rr == 2) ? a2 : a3;
                float4 o;
                o.x = fmaxf(fmaf(av.x, ni, bb.x), 0.f);
                o.y = fmaxf(fmaf(av.y, ni, bb.y), 0.f);
                o.z = fmaxf(fmaf(av.z, ni, bb.z), 0.f);
                o.w = fmaxf(fmaf(av.w, ni, bb.w), 0.f);
                ((float4*)M)[(size_t)row * 32 + cg] = o;
            }
        }
    }
}

// ---------------- mean over nodes ----------------
__global__ void mean_kernel(const float* __restrict__ h, float* __restrict__ hg) {
    __shared__ float red[256];
    int col = threadIdx.x & 127;
    int half = threadIdx.x >> 7;
    float acc = 0.f;
    for (int i = blockIdx.x * 2 + half; i < N_NODES; i += gridDim.x * 2)
        acc += h[(size_t)i * 128 + col];
    red[threadIdx.x] = acc;
    __syncthreads();
    if (threadIdx.x < 128) atomicAdd(&hg[col], red[col] + red[col + 128]);
}

// ---------------- final head: out = (hg/N) @ Wr + br ----------------
__global__ void final_kernel(const float* __restrict__ hg, const float* __restrict__ Wr,
                             const float* __restrict__ br, float* __restrict__ out) {
    int j = threadIdx.x;
    if (j < N_PRED) {
        float acc = br[j];
        const float inv = 1.0f / (float)N_NODES;
        for (int k = 0; k < HID; ++k)
            acc = fmaf(hg[k] * inv, Wr[k * N_PRED + j], acc);
        out[j] = acc;
    }
}

extern "C" void kernel_launch(void* const* d_in, const int* in_sizes, int n_in,
                              void* d_out, int out_size, void* d_ws, size_t ws_size,
                              hipStream_t stream) {
    const float* features = (const float*)d_in[0];
    const float* W0 = (const float*)d_in[1];
    const float* b0 = (const float*)d_in[2];
    const float* W1 = (const float*)d_in[3];
    const float* b1 = (const float*)d_in[4];
    const float* W2 = (const float*)d_in[5];
    const float* b2 = (const float*)d_in[6];
    const float* Wr = (const float*)d_in[7];
    const float* br = (const float*)d_in[8];
    const int* src = (const int*)d_in[9];
    const int* dst = (const int*)d_in[10];
    float* out = (float*)d_out;

    char* ws = (char*)d_ws;
    size_t off = 0;
    auto alloc = [&](size_t bytes) -> void* {
        void* p = ws + off;
        off = (off + bytes + 255) & ~(size_t)255;
        return p;
    };
    float* bufA = (float*)alloc((size_t)N_NODES * HID * 4);   // 51.2 MB
    float* bufB = (float*)alloc((size_t)N_NODES * HID * 4);   // 51.2 MB
    unsigned* degOut = (unsigned*)alloc(N_NODES * 4);
    unsigned* degIn = (unsigned*)alloc(N_NODES * 4);
    float* normOut = (float*)alloc(N_NODES * 4);
    float* normIn = (float*)alloc(N_NODES * 4);
    unsigned* rowEnd = (unsigned*)alloc(N_NODES * 4);
    unsigned* counters = (unsigned*)alloc(N_NODES * 4);
    unsigned* blockSums = (unsigned*)alloc(512 * 4);
    int* csrSrc = (int*)alloc((size_t)N_EDGES * 4);           // 6.4 MB
    float* hg = (float*)alloc(HID * 4);

    hipMemsetAsync(degOut, 0, N_NODES * 4, stream);
    hipMemsetAsync(degIn, 0, N_NODES * 4, stream);
    hipMemsetAsync(hg, 0, HID * 4, stream);

    deg_kernel<<<(N_EDGES + 255) / 256, 256, 0, stream>>>(src, dst, degOut, degIn);
    int nChunks = (N_NODES + 255) / 256;   // 391
    scan1_kernel<<<nChunks, 256, 0, stream>>>(degIn, rowEnd, blockSums);
    scan2_kernel<<<1, 512, 0, stream>>>(blockSums, nChunks);
    scan3_kernel<<<nChunks, 256, 0, stream>>>(rowEnd, counters, blockSums, degIn, degOut,
                                              normIn, normOut);
    place_kernel<<<(N_EDGES + 255) / 256, 256, 0, stream>>>(src, dst, counters, csrSrc);

    int gatherGrid = (N_NODES * 32 + 255) / 256;   // 12500
    const int rowsPerBlock = 128;
    int gemmGrid = (N_NODES + rowsPerBlock - 1) / rowsPerBlock;   // 782

    // layer 1: features -> bufA
    gather_spmm<<<gatherGrid, 256, 0, stream>>>(features, normOut, csrSrc, rowEnd, bufA);
    gemm_relu_inplace<<<gemmGrid, 256, 0, stream>>>(bufA, W0, b0, normIn, rowsPerBlock);
    // layer 2: bufA -> bufB
    gather_spmm<<<gatherGrid, 256, 0, stream>>>(bufA, normOut, csrSrc, rowEnd, bufB);
    gemm_relu_inplace<<<gemmGrid, 256, 0, stream>>>(bufB, W1, b1, normIn, rowsPerBlock);
    // layer 3: bufB -> bufA
    gather_spmm<<<gatherGrid, 256, 0, stream>>>(bufB, normOut, csrSrc, rowEnd, bufA);
    gemm_relu_inplace<<<gemmGrid, 256, 0, stream>>>(bufA, W2, b2, normIn, rowsPerBlock);

    mean_kernel<<<256, 256, 0, stream>>>(bufA, hg);
    final_kernel<<<1, 64, 0, stream>>>(hg, Wr, br, out);
}

// Round 2
// 650.119 us; speedup vs baseline: 1.5465x; 1.5465x over previous
//
#include <hip/hip_runtime.h>

#define N_NODES 100000
#define N_PAD   100032
#define N_EDGES 1600000
#define HID 128
#define N_PRED 8

typedef __attribute__((ext_vector_type(8))) short short8;
typedef __attribute__((ext_vector_type(4))) float f32x4;

__device__ __forceinline__ unsigned short f2bf(float f) {
    union { float f; unsigned u; } c; c.f = f;
    unsigned u = c.u;
    u += 0x7fffu + ((u >> 16) & 1u);   // RNE
    return (unsigned short)(u >> 16);
}
__device__ __forceinline__ float bflo(unsigned u) {
    union { unsigned u; float f; } c; c.u = u << 16; return c.f;
}
__device__ __forceinline__ float bfhi(unsigned u) {
    union { unsigned u; float f; } c; c.u = u & 0xffff0000u; return c.f;
}

// ---------------- degree histogram ----------------
__global__ void deg_kernel(const int* __restrict__ src, const int* __restrict__ dst,
                           unsigned* __restrict__ degOut, unsigned* __restrict__ degIn) {
    int e = blockIdx.x * blockDim.x + threadIdx.x;
    if (e < N_EDGES) {
        atomicAdd(&degOut[src[e]], 1u);
        atomicAdd(&degIn[dst[e]], 1u);
    }
}

// ---------------- prefix scan ----------------
__global__ void scan1_kernel(const unsigned* __restrict__ degIn,
                             unsigned* __restrict__ rowEnd,
                             unsigned* __restrict__ blockSums) {
    __shared__ unsigned tmp[256];
    int t = threadIdx.x;
    int i = blockIdx.x * 256 + t;
    unsigned v = (i < N_NODES) ? degIn[i] : 0u;
    tmp[t] = v;
    __syncthreads();
    for (int off = 1; off < 256; off <<= 1) {
        unsigned a = (t >= off) ? tmp[t - off] : 0u;
        __syncthreads();
        tmp[t] += a;
        __syncthreads();
    }
    if (i < N_NODES) rowEnd[i] = tmp[t];
    if (t == 255) blockSums[blockIdx.x] = tmp[255];
}

__global__ void scan2_kernel(unsigned* blockSums, int n) {
    __shared__ unsigned tmp[512];
    int t = threadIdx.x;
    unsigned v = (t < n) ? blockSums[t] : 0u;
    tmp[t] = v;
    __syncthreads();
    for (int off = 1; off < 512; off <<= 1) {
        unsigned a = (t >= off) ? tmp[t - off] : 0u;
        __syncthreads();
        tmp[t] += a;
        __syncthreads();
    }
    if (t < n) blockSums[t] = tmp[t];
}

__global__ void scan3_kernel(unsigned* __restrict__ rowEnd, unsigned* __restrict__ counters,
                             const unsigned* __restrict__ blockSums,
                             const unsigned* __restrict__ degIn,
                             const unsigned* __restrict__ degOut,
                             float* __restrict__ normIn, float* __restrict__ normOut) {
    int i = blockIdx.x * 256 + threadIdx.x;
    if (i >= N_NODES) return;
    unsigned add = blockIdx.x ? blockSums[blockIdx.x - 1] : 0u;
    unsigned re = rowEnd[i] + add;
    rowEnd[i] = re;
    counters[i] = re - degIn[i];
    unsigned di = degIn[i], dox = degOut[i];
    normIn[i]  = di  ? rsqrtf((float)di)  : 0.0f;
    normOut[i] = dox ? rsqrtf((float)dox) : 0.0f;
}

// ---------------- CSR edge placement ----------------
__global__ void place_kernel(const int* __restrict__ src, const int* __restrict__ dst,
                             unsigned* __restrict__ counters, int* __restrict__ csrSrc) {
    int e = blockIdx.x * blockDim.x + threadIdx.x;
    if (e < N_EDGES) {
        unsigned p = atomicAdd(&counters[dst[e]], 1u);
        csrSrc[p] = src[e];
    }
}

// ---------------- features * normOut -> bf16 ----------------
__global__ void convert_kernel(const float* __restrict__ feat, const float* __restrict__ normOut,
                               unsigned short* __restrict__ out) {
    int gid = blockIdx.x * 256 + threadIdx.x;   // over N_NODES*32
    if (gid >= N_NODES * 32) return;
    int row = gid >> 5, j = gid & 31;
    float no = normOut[row];
    float4 v = ((const float4*)feat)[(size_t)row * 32 + j];
    ushort4 o;
    o.x = f2bf(v.x * no); o.y = f2bf(v.y * no);
    o.z = f2bf(v.z * no); o.w = f2bf(v.w * no);
    ((ushort4*)out)[(size_t)row * 32 + j] = o;
}

__device__ __forceinline__ void acc8(float* a, uint4 v) {
    a[0] += bflo(v.x); a[1] += bfhi(v.x);
    a[2] += bflo(v.y); a[3] += bfhi(v.y);
    a[4] += bflo(v.z); a[5] += bfhi(v.z);
    a[6] += bflo(v.w); a[7] += bfhi(v.w);
}

// ---------------- gather (rows are pre-scaled by normOut) ----------------
__global__ void gather_bf16(const unsigned short* __restrict__ h,
                            const int* __restrict__ csrSrc,
                            const unsigned* __restrict__ rowEnd,
                            unsigned short* __restrict__ m) {
    int gid = blockIdx.x * 256 + threadIdx.x;
    int row = gid >> 4, lane = gid & 15;   // 16 lanes/row, 8 bf16 each
    if (row >= N_NODES) return;
    unsigned start = row ? rowEnd[row - 1] : 0u;
    unsigned end = rowEnd[row];
    float a[8] = {0.f, 0.f, 0.f, 0.f, 0.f, 0.f, 0.f, 0.f};
    const uint4* h4 = (const uint4*)h;
    unsigned k = start;
    for (; k + 4 <= end; k += 4) {
        int s0 = csrSrc[k], s1 = csrSrc[k + 1], s2 = csrSrc[k + 2], s3 = csrSrc[k + 3];
        uint4 v0 = h4[(size_t)s0 * 16 + lane];
        uint4 v1 = h4[(size_t)s1 * 16 + lane];
        uint4 v2 = h4[(size_t)s2 * 16 + lane];
        uint4 v3 = h4[(size_t)s3 * 16 + lane];
        acc8(a, v0); acc8(a, v1); acc8(a, v2); acc8(a, v3);
    }
    for (; k < end; ++k) {
        int s = csrSrc[k];
        uint4 v = h4[(size_t)s * 16 + lane];
        acc8(a, v);
    }
    uint4 o;
    o.x = (unsigned)f2bf(a[0]) | ((unsigned)f2bf(a[1]) << 16);
    o.y = (unsigned)f2bf(a[2]) | ((unsigned)f2bf(a[3]) << 16);
    o.z = (unsigned)f2bf(a[4]) | ((unsigned)f2bf(a[5]) << 16);
    o.w = (unsigned)f2bf(a[6]) | ((unsigned)f2bf(a[7]) << 16);
    ((uint4*)m)[(size_t)row * 16 + lane] = o;
}

// ---------------- repack W (fp32 KxN) into bf16 B-fragment order ----------------
// frag layout (16x16x32): B[k=(lane>>4)*8+j][n=lane&15], tiles: (n_tile*4+k_tile)
__global__ void repack_kernel(const float* __restrict__ W, unsigned short* __restrict__ Wp) {
    int tid = blockIdx.x * 256 + threadIdx.x;   // 2048 total
    if (tid >= 2048) return;
    int tile = tid >> 6, lane = tid & 63;
    int n_tile = tile >> 2, k_tile = tile & 3;
    int n = n_tile * 16 + (lane & 15);
    int k0 = k_tile * 32 + (lane >> 4) * 8;
    unsigned short v[8];
#pragma unroll
    for (int j = 0; j < 8; ++j)
        v[j] = f2bf(W[(size_t)(k0 + j) * 128 + n]);
    uint4 o;
    o.x = (unsigned)v[0] | ((unsigned)v[1] << 16);
    o.y = (unsigned)v[2] | ((unsigned)v[3] << 16);
    o.z = (unsigned)v[4] | ((unsigned)v[5] << 16);
    o.w = (unsigned)v[6] | ((unsigned)v[7] << 16);
    *(uint4*)&Wp[(size_t)(tile * 64 + lane) * 8] = o;
}

// ---------------- MFMA GEMM + normIn + bias + relu (+ optional normOut pre-scale) ----------------
__launch_bounds__(256)
__global__ void gemm_mfma(const unsigned short* __restrict__ M,
                          const unsigned short* __restrict__ Wp,
                          const float* __restrict__ bias,
                          const float* __restrict__ normIn,
                          const float* __restrict__ postScale,
                          unsigned short* __restrict__ Out) {
    int wave = threadIdx.x >> 6, lane = threadIdx.x & 63;
    int rowBase = blockIdx.x * 64 + wave * 16;
    int mrow = lane & 15, quad = lane >> 4;
    int arow = rowBase + mrow;
    if (arow > N_NODES - 1) arow = N_NODES - 1;   // clamp (garbage rows never stored)
    short8 a[4];
#pragma unroll
    for (int kt = 0; kt < 4; ++kt)
        a[kt] = *(const short8*)&M[(size_t)arow * 128 + kt * 32 + quad * 8];

    f32x4 acc[8];
#pragma unroll
    for (int nt = 0; nt < 8; ++nt) {
        f32x4 c = {0.f, 0.f, 0.f, 0.f};
#pragma unroll
        for (int kt = 0; kt < 4; ++kt) {
            short8 b = *(const short8*)&Wp[(size_t)((nt * 4 + kt) * 64 + lane) * 8];
            c = __builtin_amdgcn_mfma_f32_16x16x32_bf16(a[kt], b, c, 0, 0, 0);
        }
        acc[nt] = c;
    }

    int col0 = lane & 15;
#pragma unroll
    for (int r = 0; r < 4; ++r) {
        int row = rowBase + quad * 4 + r;
        if (row >= N_NODES) continue;
        float ni = normIn[row];
        float po = postScale ? postScale[row] : 1.0f;
#pragma unroll
        for (int nt = 0; nt < 8; ++nt) {
            float v = fmaxf(fmaf(acc[nt][r], ni, bias[nt * 16 + col0]), 0.f) * po;
            Out[(size_t)row * 128 + nt * 16 + col0] = f2bf(v);
        }
    }
}

// ---------------- mean over nodes (bf16 input, fp32 accum) ----------------
__global__ void mean_kernel(const unsigned short* __restrict__ h, float* __restrict__ hg) {
    __shared__ float red[4][128];
    int c2 = threadIdx.x & 63;
    int rq = threadIdx.x >> 6;
    float a0 = 0.f, a1 = 0.f;
    for (int i = blockIdx.x * 4 + rq; i < N_NODES; i += gridDim.x * 4) {
        unsigned u = *(const unsigned*)&h[(size_t)i * 128 + c2 * 2];
        a0 += bflo(u); a1 += bfhi(u);
    }
    red[rq][c2 * 2] = a0; red[rq][c2 * 2 + 1] = a1;
    __syncthreads();
    if (threadIdx.x < 128) {
        float s = red[0][threadIdx.x] + red[1][threadIdx.x] +
                  red[2][threadIdx.x] + red[3][threadIdx.x];
        atomicAdd(&hg[threadIdx.x], s);
    }
}

// ---------------- final head ----------------
__global__ void final_kernel(const float* __restrict__ hg, const float* __restrict__ Wr,
                             const float* __restrict__ br, float* __restrict__ out) {
    int j = threadIdx.x;
    if (j < N_PRED) {
        float acc = br[j];
        const float inv = 1.0f / (float)N_NODES;
        for (int k = 0; k < HID; ++k)
            acc = fmaf(hg[k] * inv, Wr[k * N_PRED + j], acc);
        out[j] = acc;
    }
}

extern "C" void kernel_launch(void* const* d_in, const int* in_sizes, int n_in,
                              void* d_out, int out_size, void* d_ws, size_t ws_size,
                              hipStream_t stream) {
    const float* features = (const float*)d_in[0];
    const float* W0 = (const float*)d_in[1];
    const float* b0 = (const float*)d_in[2];
    const float* W1 = (const float*)d_in[3];
    const float* b1 = (const float*)d_in[4];
    const float* W2 = (const float*)d_in[5];
    const float* b2 = (const float*)d_in[6];
    const float* Wr = (const float*)d_in[7];
    const float* br = (const float*)d_in[8];
    const int* src = (const int*)d_in[9];
    const int* dst = (const int*)d_in[10];
    float* out = (float*)d_out;

    char* ws = (char*)d_ws;
    size_t off = 0;
    auto alloc = [&](size_t bytes) -> void* {
        void* p = ws + off;
        off = (off + bytes + 255) & ~(size_t)255;
        return p;
    };
    unsigned short* buf0 = (unsigned short*)alloc((size_t)N_PAD * HID * 2);   // 25.6 MB
    unsigned short* buf1 = (unsigned short*)alloc((size_t)N_PAD * HID * 2);
    unsigned short* buf2 = (unsigned short*)alloc((size_t)N_PAD * HID * 2);
    unsigned short* Wp0 = (unsigned short*)alloc(128 * 128 * 2);
    unsigned short* Wp1 = (unsigned short*)alloc(128 * 128 * 2);
    unsigned short* Wp2 = (unsigned short*)alloc(128 * 128 * 2);
    unsigned* degOut = (unsigned*)alloc(N_NODES * 4);
    unsigned* degIn = (unsigned*)alloc(N_NODES * 4);
    float* normOut = (float*)alloc(N_NODES * 4);
    float* normIn = (float*)alloc(N_NODES * 4);
    unsigned* rowEnd = (unsigned*)alloc(N_NODES * 4);
    unsigned* counters = (unsigned*)alloc(N_NODES * 4);
    unsigned* blockSums = (unsigned*)alloc(512 * 4);
    int* csrSrc = (int*)alloc((size_t)N_EDGES * 4);
    float* hg = (float*)alloc(HID * 4);

    hipMemsetAsync(degOut, 0, N_NODES * 4, stream);
    hipMemsetAsync(degIn, 0, N_NODES * 4, stream);
    hipMemsetAsync(hg, 0, HID * 4, stream);

    deg_kernel<<<(N_EDGES + 255) / 256, 256, 0, stream>>>(src, dst, degOut, degIn);
    int nChunks = (N_NODES + 255) / 256;   // 391
    scan1_kernel<<<nChunks, 256, 0, stream>>>(degIn, rowEnd, blockSums);
    scan2_kernel<<<1, 512, 0, stream>>>(blockSums, nChunks);
    scan3_kernel<<<nChunks, 256, 0, stream>>>(rowEnd, counters, blockSums, degIn, degOut,
                                              normIn, normOut);
    place_kernel<<<(N_EDGES + 255) / 256, 256, 0, stream>>>(src, dst, counters, csrSrc);

    convert_kernel<<<(N_NODES * 32 + 255) / 256, 256, 0, stream>>>(features, normOut, buf0);
    repack_kernel<<<8, 256, 0, stream>>>(W0, Wp0);
    repack_kernel<<<8, 256, 0, stream>>>(W1, Wp1);
    repack_kernel<<<8, 256, 0, stream>>>(W2, Wp2);

    int gatherGrid = (N_NODES * 16 + 255) / 256;   // 6250
    int gemmGrid = (N_NODES + 63) / 64;            // 1563

    gather_bf16<<<gatherGrid, 256, 0, stream>>>(buf0, csrSrc, rowEnd, buf1);
    gemm_mfma<<<gemmGrid, 256, 0, stream>>>(buf1, Wp0, b0, normIn, normOut, buf2);
    gather_bf16<<<gatherGrid, 256, 0, stream>>>(buf2, csrSrc, rowEnd, buf0);
    gemm_mfma<<<gemmGrid, 256, 0, stream>>>(buf0, Wp1, b1, normIn, normOut, buf1);
    gather_bf16<<<gatherGrid, 256, 0, stream>>>(buf1, csrSrc, rowEnd, buf0);
    gemm_mfma<<<gemmGrid, 256, 0, stream>>>(buf0, Wp2, b2, normIn, (const float*)nullptr, buf2);

    mean_kernel<<<240, 256, 0, stream>>>(buf2, hg);
    final_kernel<<<1, 64, 0, stream>>>(hg, Wr, br, out);
}

// Round 3
// 489.173 us; speedup vs baseline: 2.0553x; 1.3290x over previous
//
#include <hip/hip_runtime.h>

#define N_NODES 100000
#define N_PAD   100032
#define N_EDGES 1600000
#define HID 128
#define N_PRED 8

#define BSHIFT 7                       // 128 nodes per bucket
#define NBUCK  782                     // ceil(100000/128)
#define CHUNK  8192                    // edges per sort block
#define NCHUNK 196                     // ceil(1600000/8192)
#define MAXB   3072                    // LDS capacity per bucket (avg 2047)

typedef __attribute__((ext_vector_type(8))) short short8;
typedef __attribute__((ext_vector_type(4))) float f32x4;

__device__ __forceinline__ unsigned short f2bf(float f) {
    union { float f; unsigned u; } c; c.f = f;
    unsigned u = c.u;
    u += 0x7fffu + ((u >> 16) & 1u);   // RNE
    return (unsigned short)(u >> 16);
}
__device__ __forceinline__ float bflo(unsigned u) {
    union { unsigned u; float f; } c; c.u = u << 16; return c.f;
}
__device__ __forceinline__ float bfhi(unsigned u) {
    union { unsigned u; float f; } c; c.u = u & 0xffff0000u; return c.f;
}

// ============ CSR build: bucket sort by dst ============

// B1: per-block bucket histogram (+ global degOut histogram for normOut)
__global__ void bucket_hist(const int* __restrict__ src, const int* __restrict__ dst,
                            unsigned* __restrict__ blockHist, unsigned* __restrict__ degOut) {
    __shared__ unsigned hist[NBUCK];
    for (int i = threadIdx.x; i < NBUCK; i += 256) hist[i] = 0u;
    __syncthreads();
    int base = blockIdx.x * CHUNK;
    int lim = min(base + CHUNK, N_EDGES);
    for (int e = base + threadIdx.x; e < lim; e += 256) {
        atomicAdd(&hist[((unsigned)dst[e]) >> BSHIFT], 1u);
        atomicAdd(&degOut[src[e]], 1u);
    }
    __syncthreads();
    for (int i = threadIdx.x; i < NBUCK; i += 256)
        blockHist[(size_t)i * NCHUNK + blockIdx.x] = hist[i];   // bucket-major
}

__global__ void normout_kernel(const unsigned* __restrict__ degOut, float* __restrict__ normOut) {
    int i = blockIdx.x * 256 + threadIdx.x;
    if (i < N_NODES) {
        unsigned d = degOut[i];
        normOut[i] = d ? rsqrtf((float)d) : 0.0f;
    }
}

// B2a: bucket totals
__global__ void bucket_total(const unsigned* __restrict__ blockHist, unsigned* __restrict__ bucketTotal) {
    __shared__ unsigned red[256];
    int t = threadIdx.x;
    red[t] = (t < NCHUNK) ? blockHist[(size_t)blockIdx.x * NCHUNK + t] : 0u;
    __syncthreads();
    for (int s = 128; s > 0; s >>= 1) {
        if (t < s) red[t] += red[t + s];
        __syncthreads();
    }
    if (t == 0) bucketTotal[blockIdx.x] = red[0];
}

// B2b: exclusive scan of bucket totals -> bucketBase (single block)
__global__ void bucket_scan(const unsigned* __restrict__ bucketTotal, unsigned* __restrict__ bucketBase) {
    __shared__ unsigned tmp[1024];
    int t = threadIdx.x;
    unsigned v = (t < NBUCK) ? bucketTotal[t] : 0u;
    tmp[t] = v;
    __syncthreads();
    for (int off = 1; off < 1024; off <<= 1) {
        unsigned a = (t >= off) ? tmp[t - off] : 0u;
        __syncthreads();
        tmp[t] += a;
        __syncthreads();
    }
    if (t < NBUCK) bucketBase[t] = tmp[t] - v;   // exclusive
}

// B2c: per-bucket exclusive scan of per-block counts + bucketBase -> absolute cursors
__global__ void bucket_cursor(unsigned* __restrict__ blockHist, const unsigned* __restrict__ bucketBase) {
    __shared__ unsigned tmp[256];
    int t = threadIdx.x;
    unsigned v = (t < NCHUNK) ? blockHist[(size_t)blockIdx.x * NCHUNK + t] : 0u;
    tmp[t] = v;
    __syncthreads();
    for (int off = 1; off < 256; off <<= 1) {
        unsigned a = (t >= off) ? tmp[t - off] : 0u;
        __syncthreads();
        tmp[t] += a;
        __syncthreads();
    }
    if (t < NCHUNK)
        blockHist[(size_t)blockIdx.x * NCHUNK + t] = tmp[t] - v + bucketBase[blockIdx.x];
}

// B3: scatter packed edges into bucket order (block-owned runs -> L2 line merging)
__global__ void bucket_scatter(const int* __restrict__ src, const int* __restrict__ dst,
                               const unsigned* __restrict__ blockHist, unsigned* __restrict__ bucketed) {
    __shared__ unsigned cursor[NBUCK];
    for (int i = threadIdx.x; i < NBUCK; i += 256)
        cursor[i] = blockHist[(size_t)i * NCHUNK + blockIdx.x];
    __syncthreads();
    int base = blockIdx.x * CHUNK;
    int lim = min(base + CHUNK, N_EDGES);
    for (int e = base + threadIdx.x; e < lim; e += 256) {
        unsigned d = (unsigned)dst[e];
        unsigned p = atomicAdd(&cursor[d >> BSHIFT], 1u);
        bucketed[p] = ((d & 127u) << 17) | (unsigned)src[e];   // src < 2^17
    }
}

// C: per-bucket placement in LDS; emits csrSrc (coalesced), rowEnd, normIn
__global__ void bucket_place(const unsigned* __restrict__ bucketed,
                             const unsigned* __restrict__ bucketBase,
                             int* __restrict__ csrSrc, unsigned* __restrict__ rowEnd,
                             float* __restrict__ normIn) {
    __shared__ unsigned cnt128[128], cur[128];
    __shared__ unsigned eb[MAXB], ob[MAXB];
    int b = blockIdx.x;
    unsigned s0 = bucketBase[b];
    unsigned s1 = (b + 1 < NBUCK) ? bucketBase[b + 1] : (unsigned)N_EDGES;
    int cnt = (int)(s1 - s0);
    bool fits = cnt <= MAXB;
    int t = threadIdx.x;
    if (t < 128) cnt128[t] = 0u;
    __syncthreads();
    for (int i = t; i < cnt; i += 256) {
        unsigned v = bucketed[s0 + i];
        if (fits) eb[i] = v;
        atomicAdd(&cnt128[v >> 17], 1u);
    }
    __syncthreads();
    unsigned deg = (t < 128) ? cnt128[t] : 0u;
    __syncthreads();
    for (int off = 1; off < 128; off <<= 1) {
        unsigned a = (t < 128 && t >= off) ? cnt128[t - off] : 0u;
        __syncthreads();
        if (t < 128) cnt128[t] += a;
        __syncthreads();
    }
    if (t < 128) {
        unsigned incl = cnt128[t];
        cur[t] = incl - deg;               // local exclusive
        int node = b * 128 + t;
        if (node < N_NODES) {
            rowEnd[node] = s0 + incl;      // global inclusive prefix
            normIn[node] = deg ? rsqrtf((float)deg) : 0.0f;
        }
    }
    __syncthreads();
    if (fits) {
        for (int i = t; i < cnt; i += 256) {
            unsigned v = eb[i];
            unsigned p = atomicAdd(&cur[v >> 17], 1u);
            ob[p] = v & 0x1FFFFu;
        }
        __syncthreads();
        for (int i = t; i < cnt; i += 256)
            csrSrc[s0 + i] = (int)ob[i];
    } else {
        for (int i = t; i < cnt; i += 256) {
            unsigned v = bucketed[s0 + i];
            unsigned p = atomicAdd(&cur[v >> 17], 1u);
            csrSrc[s0 + p] = (int)(v & 0x1FFFFu);
        }
    }
}

// ============ datapath ============

__global__ void convert_kernel(const float* __restrict__ feat, const float* __restrict__ normOut,
                               unsigned short* __restrict__ out) {
    int gid = blockIdx.x * 256 + threadIdx.x;
    if (gid >= N_NODES * 32) return;
    int row = gid >> 5, j = gid & 31;
    float no = normOut[row];
    float4 v = ((const float4*)feat)[(size_t)row * 32 + j];
    ushort4 o;
    o.x = f2bf(v.x * no); o.y = f2bf(v.y * no);
    o.z = f2bf(v.z * no); o.w = f2bf(v.w * no);
    ((ushort4*)out)[(size_t)row * 32 + j] = o;
}

__device__ __forceinline__ void acc8(float* a, uint4 v) {
    a[0] += bflo(v.x); a[1] += bfhi(v.x);
    a[2] += bflo(v.y); a[3] += bfhi(v.y);
    a[4] += bflo(v.z); a[5] += bfhi(v.z);
    a[6] += bflo(v.w); a[7] += bfhi(v.w);
}

// gather with 8 loads in flight per lane (rows pre-scaled by normOut)
__global__ void gather_bf16(const unsigned short* __restrict__ h,
                            const int* __restrict__ csrSrc,
                            const unsigned* __restrict__ rowEnd,
                            unsigned short* __restrict__ m) {
    int gid = blockIdx.x * 256 + threadIdx.x;
    int row = gid >> 4, lane = gid & 15;
    if (row >= N_NODES) return;
    unsigned start = row ? rowEnd[row - 1] : 0u;
    unsigned end = rowEnd[row];
    float a[8] = {0.f, 0.f, 0.f, 0.f, 0.f, 0.f, 0.f, 0.f};
    const uint4* h4 = (const uint4*)h;
    unsigned k = start;
    for (; k + 8 <= end; k += 8) {
        int s[8];
#pragma unroll
        for (int j = 0; j < 8; ++j) s[j] = csrSrc[k + j];
        uint4 v[8];
#pragma unroll
        for (int j = 0; j < 8; ++j) v[j] = h4[(size_t)s[j] * 16 + lane];
#pragma unroll
        for (int j = 0; j < 8; ++j) acc8(a, v[j]);
    }
    if (k + 4 <= end) {
        int s[4];
#pragma unroll
        for (int j = 0; j < 4; ++j) s[j] = csrSrc[k + j];
        uint4 v[4];
#pragma unroll
        for (int j = 0; j < 4; ++j) v[j] = h4[(size_t)s[j] * 16 + lane];
#pragma unroll
        for (int j = 0; j < 4; ++j) acc8(a, v[j]);
        k += 4;
    }
    for (; k < end; ++k) {
        uint4 v = h4[(size_t)csrSrc[k] * 16 + lane];
        acc8(a, v);
    }
    uint4 o;
    o.x = (unsigned)f2bf(a[0]) | ((unsigned)f2bf(a[1]) << 16);
    o.y = (unsigned)f2bf(a[2]) | ((unsigned)f2bf(a[3]) << 16);
    o.z = (unsigned)f2bf(a[4]) | ((unsigned)f2bf(a[5]) << 16);
    o.w = (unsigned)f2bf(a[6]) | ((unsigned)f2bf(a[7]) << 16);
    ((uint4*)m)[(size_t)row * 16 + lane] = o;
}

// repack W (fp32 KxN) into bf16 B-fragment order
__global__ void repack_kernel(const float* __restrict__ W, unsigned short* __restrict__ Wp) {
    int tid = blockIdx.x * 256 + threadIdx.x;
    if (tid >= 2048) return;
    int tile = tid >> 6, lane = tid & 63;
    int n_tile = tile >> 2, k_tile = tile & 3;
    int n = n_tile * 16 + (lane & 15);
    int k0 = k_tile * 32 + (lane >> 4) * 8;
    unsigned short v[8];
#pragma unroll
    for (int j = 0; j < 8; ++j)
        v[j] = f2bf(W[(size_t)(k0 + j) * 128 + n]);
    uint4 o;
    o.x = (unsigned)v[0] | ((unsigned)v[1] << 16);
    o.y = (unsigned)v[2] | ((unsigned)v[3] << 16);
    o.z = (unsigned)v[4] | ((unsigned)v[5] << 16);
    o.w = (unsigned)v[6] | ((unsigned)v[7] << 16);
    *(uint4*)&Wp[(size_t)(tile * 64 + lane) * 8] = o;
}

__launch_bounds__(256)
__global__ void gemm_mfma(const unsigned short* __restrict__ M,
                          const unsigned short* __restrict__ Wp,
                          const float* __restrict__ bias,
                          const float* __restrict__ normIn,
                          const float* __restrict__ postScale,
                          unsigned short* __restrict__ Out) {
    int wave = threadIdx.x >> 6, lane = threadIdx.x & 63;
    int rowBase = blockIdx.x * 64 + wave * 16;
    int mrow = lane & 15, quad = lane >> 4;
    int arow = rowBase + mrow;
    if (arow > N_NODES - 1) arow = N_NODES - 1;
    short8 a[4];
#pragma unroll
    for (int kt = 0; kt < 4; ++kt)
        a[kt] = *(const short8*)&M[(size_t)arow * 128 + kt * 32 + quad * 8];

    f32x4 acc[8];
#pragma unroll
    for (int nt = 0; nt < 8; ++nt) {
        f32x4 c = {0.f, 0.f, 0.f, 0.f};
#pragma unroll
        for (int kt = 0; kt < 4; ++kt) {
            short8 b = *(const short8*)&Wp[(size_t)((nt * 4 + kt) * 64 + lane) * 8];
            c = __builtin_amdgcn_mfma_f32_16x16x32_bf16(a[kt], b, c, 0, 0, 0);
        }
        acc[nt] = c;
    }

    int col0 = lane & 15;
#pragma unroll
    for (int r = 0; r < 4; ++r) {
        int row = rowBase + quad * 4 + r;
        if (row >= N_NODES) continue;
        float ni = normIn[row];
        float po = postScale ? postScale[row] : 1.0f;
#pragma unroll
        for (int nt = 0; nt < 8; ++nt) {
            float v = fmaxf(fmaf(acc[nt][r], ni, bias[nt * 16 + col0]), 0.f) * po;
            Out[(size_t)row * 128 + nt * 16 + col0] = f2bf(v);
        }
    }
}

__global__ void mean_kernel(const unsigned short* __restrict__ h, float* __restrict__ hg) {
    __shared__ float red[4][128];
    int c2 = threadIdx.x & 63;
    int rq = threadIdx.x >> 6;
    float a0 = 0.f, a1 = 0.f;
    for (int i = blockIdx.x * 4 + rq; i < N_NODES; i += gridDim.x * 4) {
        unsigned u = *(const unsigned*)&h[(size_t)i * 128 + c2 * 2];
        a0 += bflo(u); a1 += bfhi(u);
    }
    red[rq][c2 * 2] = a0; red[rq][c2 * 2 + 1] = a1;
    __syncthreads();
    if (threadIdx.x < 128) {
        float s = red[0][threadIdx.x] + red[1][threadIdx.x] +
                  red[2][threadIdx.x] + red[3][threadIdx.x];
        atomicAdd(&hg[threadIdx.x], s);
    }
}

__global__ void final_kernel(const float* __restrict__ hg, const float* __restrict__ Wr,
                             const float* __restrict__ br, float* __restrict__ out) {
    int j = threadIdx.x;
    if (j < N_PRED) {
        float acc = br[j];
        const float inv = 1.0f / (float)N_NODES;
        for (int k = 0; k < HID; ++k)
            acc = fmaf(hg[k] * inv, Wr[k * N_PRED + j], acc);
        out[j] = acc;
    }
}

extern "C" void kernel_launch(void* const* d_in, const int* in_sizes, int n_in,
                              void* d_out, int out_size, void* d_ws, size_t ws_size,
                              hipStream_t stream) {
    const float* features = (const float*)d_in[0];
    const float* W0 = (const float*)d_in[1];
    const float* b0 = (const float*)d_in[2];
    const float* W1 = (const float*)d_in[3];
    const float* b1 = (const float*)d_in[4];
    const float* W2 = (const float*)d_in[5];
    const float* b2 = (const float*)d_in[6];
    const float* Wr = (const float*)d_in[7];
    const float* br = (const float*)d_in[8];
    const int* src = (const int*)d_in[9];
    const int* dst = (const int*)d_in[10];
    float* out = (float*)d_out;

    char* ws = (char*)d_ws;
    size_t off = 0;
    auto alloc = [&](size_t bytes) -> void* {
        void* p = ws + off;
        off = (off + bytes + 255) & ~(size_t)255;
        return p;
    };
    unsigned short* buf0 = (unsigned short*)alloc((size_t)N_PAD * HID * 2);
    unsigned short* buf1 = (unsigned short*)alloc((size_t)N_PAD * HID * 2);
    unsigned short* buf2 = (unsigned short*)alloc((size_t)N_PAD * HID * 2);
    unsigned short* Wp0 = (unsigned short*)alloc(128 * 128 * 2);
    unsigned short* Wp1 = (unsigned short*)alloc(128 * 128 * 2);
    unsigned short* Wp2 = (unsigned short*)alloc(128 * 128 * 2);
    unsigned* degOut = (unsigned*)alloc(N_NODES * 4);
    float* normOut = (float*)alloc(N_NODES * 4);
    float* normIn = (float*)alloc(N_NODES * 4);
    unsigned* rowEnd = (unsigned*)alloc(N_NODES * 4);
    unsigned* blockHist = (unsigned*)alloc((size_t)NBUCK * NCHUNK * 4);
    unsigned* bucketTotal = (unsigned*)alloc(NBUCK * 4);
    unsigned* bucketBase = (unsigned*)alloc((NBUCK + 1) * 4);
    unsigned* bucketed = (unsigned*)alloc((size_t)N_EDGES * 4);
    int* csrSrc = (int*)alloc((size_t)N_EDGES * 4);
    float* hg = (float*)alloc(HID * 4);

    hipMemsetAsync(degOut, 0, N_NODES * 4, stream);
    hipMemsetAsync(hg, 0, HID * 4, stream);

    bucket_hist<<<NCHUNK, 256, 0, stream>>>(src, dst, blockHist, degOut);
    normout_kernel<<<(N_NODES + 255) / 256, 256, 0, stream>>>(degOut, normOut);
    bucket_total<<<NBUCK, 256, 0, stream>>>(blockHist, bucketTotal);
    bucket_scan<<<1, 1024, 0, stream>>>(bucketTotal, bucketBase);
    bucket_cursor<<<NBUCK, 256, 0, stream>>>(blockHist, bucketBase);
    bucket_scatter<<<NCHUNK, 256, 0, stream>>>(src, dst, blockHist, bucketed);
    bucket_place<<<NBUCK, 256, 0, stream>>>(bucketed, bucketBase, csrSrc, rowEnd, normIn);

    convert_kernel<<<(N_NODES * 32 + 255) / 256, 256, 0, stream>>>(features, normOut, buf0);
    repack_kernel<<<8, 256, 0, stream>>>(W0, Wp0);
    repack_kernel<<<8, 256, 0, stream>>>(W1, Wp1);
    repack_kernel<<<8, 256, 0, stream>>>(W2, Wp2);

    int gatherGrid = (N_NODES * 16 + 255) / 256;
    int gemmGrid = (N_NODES + 63) / 64;

    gather_bf16<<<gatherGrid, 256, 0, stream>>>(buf0, csrSrc, rowEnd, buf1);
    gemm_mfma<<<gemmGrid, 256, 0, stream>>>(buf1, Wp0, b0, normIn, normOut, buf2);
    gather_bf16<<<gatherGrid, 256, 0, stream>>>(buf2, csrSrc, rowEnd, buf0);
    gemm_mfma<<<gemmGrid, 256, 0, stream>>>(buf0, Wp1, b1, normIn, normOut, buf1);
    gather_bf16<<<gatherGrid, 256, 0, stream>>>(buf1, csrSrc, rowEnd, buf0);
    gemm_mfma<<<gemmGrid, 256, 0, stream>>>(buf0, Wp2, b2, normIn, (const float*)nullptr, buf2);

    mean_kernel<<<240, 256, 0, stream>>>(buf2, hg);
    final_kernel<<<1, 64, 0, stream>>>(hg, Wr, br, out);
}